// Round 11
// baseline (2259.265 us; speedup 1.0000x reference)
//
#include <hip/hip_runtime.h>

#define NN 100000
#define EE 1600000
#define NPART 8                   // dst-space partitions
#define PSZ (NN / NPART)          // 12500 nodes per partition
#define NI4 (EE / 4)              // 400000 int4 records in dst/src
#define SUBW 196                  // dst nodes per sub-bucket (64 per partition)
#define NSB (NPART * 64)          // 512 sub-buckets
#define SCAP 4096                 // records per sub-bucket (exp 3136, +17 sigma)
#define RCAP 8192                 // csr slots per sub-bucket region (exp ~3960)
#define LBCAP 96                  // LDS bin capacity (round-0 proven)
#define WTB 48                    // 3 matrices x 16 (32x32) transpose tiles
#define AGGB (NN / 4)             // 25000 aggregate blocks
#define GEMB 1563                 // gemm block family (6250 16-row waves + 2 idle)
#define NG16 (NN / 16)            // 6250 16-row groups (exact)

typedef __attribute__((ext_vector_type(8))) short bf16x8;
typedef __attribute__((ext_vector_type(4))) float f32x4;

// bf16 helpers (exact unpack; RN pack)
__device__ inline unsigned int f2bf2(float a, float b) {  // pack (a=low, b=high)
    unsigned int ua = __float_as_uint(a);
    unsigned int ub = __float_as_uint(b);
    ua = (ua + 0x7fffu + ((ua >> 16) & 1u)) >> 16;
    ub = (ub + 0x7fffu + ((ub >> 16) & 1u)) >> 16;
    return ua | (ub << 16);
}
__device__ inline unsigned short f2bf(float a) {
    unsigned int u = __float_as_uint(a);
    return (unsigned short)((u + 0x7fffu + ((u >> 16) & 1u)) >> 16);
}
__device__ inline float2 bf2f2(unsigned int u) {
    return make_float2(__uint_as_float(u << 16), __uint_as_float(u & 0xffff0000u));
}

// ---------------- K1: wt-build (blocks 0-47) + round-0 filterbin (48-559) ----

__global__ __launch_bounds__(256) void fbwt_kernel(const int4* __restrict__ src4,
                                                   const int4* __restrict__ dst4,
                                                   int* __restrict__ gcur2,
                                                   uint2* __restrict__ buckets2,
                                                   const float* __restrict__ W1,
                                                   const float* __restrict__ W2,
                                                   const float* __restrict__ W3,
                                                   unsigned short* __restrict__ wt1,
                                                   unsigned short* __restrict__ wt2,
                                                   unsigned short* __restrict__ wt3,
                                                   unsigned int* __restrict__ hbA,
                                                   unsigned int* __restrict__ hbB,
                                                   float* __restrict__ dinv) {
    __shared__ uint2 bins[64][LBCAP];
    __shared__ int bcnt[64];
    __shared__ int gbase[64];
    __shared__ float tile[32][33];
    const int bx = blockIdx.x;

    if (bx < WTB) {                       // ---- wt-build blocks ----
        const int m = bx >> 4;            // matrix 0..2
        const int tl = bx & 15;           // 32x32 tile
        const int ti = tl >> 2, tj = tl & 3;
        const float* W = m == 0 ? W1 : (m == 1 ? W2 : W3);
        unsigned short* wt = m == 0 ? wt1 : (m == 1 ? wt2 : wt3);
        const int r = threadIdx.x >> 5, c = threadIdx.x & 31;
#pragma unroll
        for (int rr = r; rr < 32; rr += 8)     // coalesced read of W[k][n]
            tile[rr][c] = W[(ti * 32 + rr) * 128 + tj * 32 + c];
        __syncthreads();
#pragma unroll
        for (int rr = r; rr < 32; rr += 8)     // coalesced write of wt[n][k]
            wt[(size_t)(tj * 32 + rr) * 128 + ti * 32 + c] = f2bf(tile[c][rr]);
        if (bx == 0) {
            if (threadIdx.x < 64) {
                hbA[(size_t)NN * 64 + threadIdx.x] = 0;   // sentinel rows
                hbB[(size_t)NN * 64 + threadIdx.x] = 0;
            }
            if (threadIdx.x == 64) dinv[NN] = 0.0f;
        }
        return;
    }

    // ---- filter blocks (round-0 exact config: 512 blocks, LBCAP 96) ----
    const int fb = bx - WTB;
    const int p = fb >> 6;
    const int c = fb & 63;
    if (threadIdx.x < 64) bcnt[threadIdx.x] = 0;
    __syncthreads();
    const int lo = p * PSZ, hi = lo + PSZ;
    const int chunk4 = NI4 / 64;                    // 6250, exact
    const int a0 = c * chunk4, a1 = a0 + chunk4;
    for (int i = a0 + threadIdx.x; i < a1; i += 256) {
        int4 d4 = dst4[i];
        bool m0 = (d4.x >= lo && d4.x < hi);
        bool m1 = (d4.y >= lo && d4.y < hi);
        bool m2 = (d4.z >= lo && d4.z < hi);
        bool m3 = (d4.w >= lo && d4.w < hi);
        if (!(m0 | m1 | m2 | m3)) continue;
        int4 s4 = src4[i];
        int ss[4] = {s4.x, s4.y, s4.z, s4.w};
        int dd[4] = {d4.x, d4.y, d4.z, d4.w};
        bool mm[4] = {m0, m1, m2, m3};
#pragma unroll
        for (int k = 0; k < 4; ++k) {
            if (!mm[k]) continue;
            int li = (dd[k] - lo) / SUBW;           // 0..63
            int pos = atomicAdd(&bcnt[li], 1);
            if (pos < LBCAP) {
                bins[li][pos] = make_uint2((unsigned)ss[k], (unsigned)dd[k]);
            } else {                                 // rare overflow: direct append
                int sb = p * 64 + li;
                int gp = atomicAdd(&gcur2[sb], 1);
                buckets2[(size_t)sb * SCAP + gp] = make_uint2((unsigned)ss[k], (unsigned)dd[k]);
            }
        }
    }
    __syncthreads();
    if (threadIdx.x < 64) {
        int cc = min(bcnt[threadIdx.x], LBCAP);
        gbase[threadIdx.x] = atomicAdd(&gcur2[p * 64 + threadIdx.x], cc);
        bcnt[threadIdx.x] = cc;
    }
    __syncthreads();
    for (int b = 0; b < 64; ++b) {
        const int cc = bcnt[b];
        uint2* outp = buckets2 + (size_t)(p * 64 + b) * SCAP + gbase[b];
        for (int i = threadIdx.x; i < cc; i += 256) outp[i] = bins[b][i];
    }
}

// ---------------- hoisted GEMM body (layer 1 only; raw output) ---------------
// 64 rows per wave, W-fragments hoisted. Lives in sort3_gemm1 only, so its
// register pressure never touches the aggregate kernels.

__device__ __forceinline__ void gemm64_raw(int wave, const float* __restrict__ x0,
                                           const unsigned short* __restrict__ wt,
                                           unsigned int* __restrict__ hb) {
    const int base = wave * 64;
    if (base >= NN) return;
    const int lane = threadIdx.x & 63;
    const int r = lane & 15;
    const int q = lane >> 4;
    const unsigned short* wrow = wt + (size_t)r * 128 + q * 8;
    bf16x8 wfr[4][8];
#pragma unroll
    for (int kc = 0; kc < 4; ++kc)
#pragma unroll
        for (int nt = 0; nt < 8; ++nt)
            wfr[kc][nt] = *(const bf16x8*)(wrow + (size_t)nt * 16 * 128 + kc * 32);
#pragma unroll
    for (int tt = 0; tt < 4; ++tt) {
        const int m0 = base + tt * 16;
        if (m0 >= NN) break;
        f32x4 acc[8] = {};
#pragma unroll
        for (int kc = 0; kc < 4; ++kc) {
            const float* xrow = x0 + (size_t)(m0 + r) * 128 + q * 8 + kc * 32;
            float4 a = *(const float4*)xrow;
            float4 b = *(const float4*)(xrow + 4);
            unsigned short tmp[8] = {f2bf(a.x), f2bf(a.y), f2bf(a.z), f2bf(a.w),
                                     f2bf(b.x), f2bf(b.y), f2bf(b.z), f2bf(b.w)};
            bf16x8 xf = *(const bf16x8*)tmp;
#pragma unroll
            for (int nt = 0; nt < 8; ++nt)
                acc[nt] = __builtin_amdgcn_mfma_f32_16x16x32_bf16(wfr[kc][nt], xf, acc[nt], 0, 0, 0);
        }
        const int orow = m0 + r;
        unsigned int* hrow = hb + (size_t)orow * 64;
#pragma unroll
        for (int nt = 0; nt < 8; ++nt) {
            int n = nt * 16 + q * 4;
            *(uint2*)(hrow + (n >> 1)) =
                make_uint2(f2bf2(acc[nt][0], acc[nt][1]), f2bf2(acc[nt][2], acc[nt][3]));
        }
    }
}

// ---------------- 16-row scaled GEMM body (fused kernels; low VGPR) ----------
// Round-0 granularity, wf loaded per use: keeps the FUSED kernel's VGPR max
// ~70 so co-resident aggregate blocks keep their occupancy (round-5 lesson:
// one kernel = one VGPR allocation).

__device__ __forceinline__ void gemm16_scaled(int m0, const unsigned int* __restrict__ xact,
                                              const unsigned short* __restrict__ wt,
                                              const float* __restrict__ dinv,
                                              unsigned int* __restrict__ hbout) {
    const int lane = threadIdx.x & 63;
    const int r = lane & 15;
    const int q = lane >> 4;
    const unsigned short* wrow = wt + (size_t)r * 128 + q * 8;
    f32x4 acc[8] = {};
#pragma unroll
    for (int kc = 0; kc < 4; ++kc) {
        const unsigned short* xrow =
            (const unsigned short*)xact + (size_t)(m0 + r) * 128 + q * 8 + kc * 32;
        bf16x8 xf = *(const bf16x8*)xrow;
#pragma unroll
        for (int nt = 0; nt < 8; ++nt) {
            bf16x8 wf = *(const bf16x8*)(wrow + (size_t)nt * 16 * 128 + kc * 32);
            acc[nt] = __builtin_amdgcn_mfma_f32_16x16x32_bf16(wf, xf, acc[nt], 0, 0, 0);
        }
    }
    const float dvr = dinv[m0 + r];
    unsigned int* hrow = hbout + (size_t)(m0 + r) * 64;
#pragma unroll
    for (int nt = 0; nt < 8; ++nt) {
        int n = nt * 16 + q * 4;
        *(uint2*)(hrow + (n >> 1)) =
            make_uint2(f2bf2(acc[nt][0] * dvr, acc[nt][1] * dvr),
                       f2bf2(acc[nt][2] * dvr, acc[nt][3] * dvr));
    }
}

// spin until the 4 aggregate blocks covering rows [g*16, g*16+16) are done
__device__ __forceinline__ void wait_group16(const int* __restrict__ cnt, int g) {
    while (__hip_atomic_load(cnt + g, __ATOMIC_ACQUIRE, __HIP_MEMORY_SCOPE_AGENT) < 4)
        __builtin_amdgcn_s_sleep(16);
}

// ---------------- K2: sort3 (blocks 0-511) + layer-1 GEMM (512-902) ----------
// Round-0 exact sort3: compact padded rows, info[d]=(rowoff<<8)|deg, dinv[d].

__global__ __launch_bounds__(256, 2) void sort3_gemm1_kernel(const uint2* __restrict__ buckets2,
                                                             const int* __restrict__ gcur2,
                                                             int* __restrict__ csr,
                                                             int* __restrict__ info,
                                                             float* __restrict__ dinv,
                                                             const float* __restrict__ x0,
                                                             const unsigned short* __restrict__ wt1,
                                                             unsigned int* __restrict__ hbA) {
    __shared__ int hist[256];
    __shared__ int pscan[256];
    __shared__ int lcur[256];
    __shared__ int staged[RCAP];
    if (blockIdx.x >= 512) {   // layer-1 GEMM blocks (raw output to hbA)
        const int wave = (blockIdx.x - 512) * 4 + (threadIdx.x >> 6);
        gemm64_raw(wave, x0, wt1, hbA);
        return;
    }
    const int sb = blockIdx.x;
    const int li = sb & 63;
    const int base_node = (sb >> 6) * PSZ + li * SUBW;
    const int nnodes = min(SUBW, PSZ - li * SUBW);  // 196 (152 for last)
    const int scnt = gcur2[sb];
    const uint2* bk = buckets2 + (size_t)sb * SCAP;
    const int t = threadIdx.x;
    hist[t] = 0;
    __syncthreads();
    for (int i = t; i < scnt; i += 256) atomicAdd(&hist[(int)bk[i].y - base_node], 1);
    __syncthreads();
    const int padded = (t < nnodes) ? ((hist[t] + 7) & ~7) : 0;
    pscan[t] = padded;
    __syncthreads();
    for (int off = 1; off < 256; off <<= 1) {
        int v = (t >= off) ? pscan[t - off] : 0;
        __syncthreads();
        pscan[t] += v;
        __syncthreads();
    }
    const int rstart = pscan[t] - padded;           // exclusive scan
    lcur[t] = rstart;
    __syncthreads();
    const int total = pscan[255];                   // multiple of 8
    for (int i = t; i < total; i += 256) staged[i] = NN;  // sentinel fill
    __syncthreads();
    for (int i = t; i < scnt; i += 256) {
        uint2 r = bk[i];
        int pos = atomicAdd(&lcur[(int)r.y - base_node], 1);
        staged[pos] = (int)r.x;
    }
    __syncthreads();
    int4* co = (int4*)(csr + (size_t)sb * RCAP);
    for (int i = t; i < (total >> 2); i += 256) co[i] = ((const int4*)staged)[i];
    if (t < nnodes) {
        int dg = hist[t];
        info[base_node + t] = ((sb * RCAP + rstart) << 8) | dg;   // rowoff<24b, deg<8b
        dinv[base_node + t] = rsqrtf(1.0f + (float)dg);
    }
}

// ---------------- fused 1: weighted agg (layer 1) + gemm2 --------------------
// blocks [0,25000): round-10 weighted aggregate; hbA raw h -> xact; each block
//   increments cnt[blk>>2] (release) when its 4 rows are written.
// blocks [25000,26563): gemm2 waves; wave ws handles rows [ws*16, ws*16+16),
//   spins on cnt (acquire) until the 4 producer blocks are done, then scaled
//   GEMM xact @ wt2 -> hbB. Deadlock-free: 1563 gemm blocks < 2048 resident
//   capacity, so aggregate blocks always have slots to progress.

__global__ __launch_bounds__(256) void aggw_gemm2_kernel(const unsigned int* __restrict__ hbA,
                                                         const int* __restrict__ csr,
                                                         const int* __restrict__ info,
                                                         const float* __restrict__ dinv,
                                                         const float2* __restrict__ bias2,
                                                         unsigned int* __restrict__ xact,
                                                         const unsigned short* __restrict__ wt2,
                                                         unsigned int* __restrict__ hbB,
                                                         int* __restrict__ cnt) {
    if (blockIdx.x >= AGGB) {             // ---- gemm2 family ----
        const int ws = (blockIdx.x - AGGB) * 4 + (threadIdx.x >> 6);
        const int m0 = ws * 16;
        if (m0 >= NN) return;
        wait_group16(cnt, ws);
        __threadfence();
        gemm16_scaled(m0, xact, wt2, dinv, hbB);
        return;
    }
    const int d = blockIdx.x * 4 + (threadIdx.x >> 6);
    const int j = threadIdx.x & 63;     // lane
    const int ifo = info[d];
    int e = ifo >> 8;
    const int end = e + (((ifo & 255) + 7) & ~7);
    const float dv = dinv[d];
    float2 acc;
    {
        float2 s = bf2f2(hbA[(size_t)d * 64 + j]);
        acc.x = dv * s.x;
        acc.y = dv * s.y;
    }
    for (; e + 16 <= end; e += 16) {
        int4 c0 = *(const int4*)(csr + e);
        int4 c1 = *(const int4*)(csr + e + 4);
        int4 c2 = *(const int4*)(csr + e + 8);
        int4 c3 = *(const int4*)(csr + e + 12);
        unsigned int v0 = hbA[(size_t)c0.x * 64 + j];
        unsigned int v1 = hbA[(size_t)c0.y * 64 + j];
        unsigned int v2 = hbA[(size_t)c0.z * 64 + j];
        unsigned int v3 = hbA[(size_t)c0.w * 64 + j];
        unsigned int v4 = hbA[(size_t)c1.x * 64 + j];
        unsigned int v5 = hbA[(size_t)c1.y * 64 + j];
        unsigned int v6 = hbA[(size_t)c1.z * 64 + j];
        unsigned int v7 = hbA[(size_t)c1.w * 64 + j];
        unsigned int v8 = hbA[(size_t)c2.x * 64 + j];
        unsigned int v9 = hbA[(size_t)c2.y * 64 + j];
        unsigned int va = hbA[(size_t)c2.z * 64 + j];
        unsigned int vb = hbA[(size_t)c2.w * 64 + j];
        unsigned int vc = hbA[(size_t)c3.x * 64 + j];
        unsigned int vd = hbA[(size_t)c3.y * 64 + j];
        unsigned int ve = hbA[(size_t)c3.z * 64 + j];
        unsigned int vf = hbA[(size_t)c3.w * 64 + j];
        float w0 = dinv[c0.x], w1 = dinv[c0.y], w2 = dinv[c0.z], w3 = dinv[c0.w];
        float w4 = dinv[c1.x], w5 = dinv[c1.y], w6 = dinv[c1.z], w7 = dinv[c1.w];
        float w8 = dinv[c2.x], w9 = dinv[c2.y], wa = dinv[c2.z], wb = dinv[c2.w];
        float wc = dinv[c3.x], wd = dinv[c3.y], we = dinv[c3.z], wf = dinv[c3.w];
        float2 f0 = bf2f2(v0), f1 = bf2f2(v1), f2 = bf2f2(v2), f3 = bf2f2(v3);
        float2 f4 = bf2f2(v4), f5 = bf2f2(v5), f6 = bf2f2(v6), f7 = bf2f2(v7);
        float2 f8 = bf2f2(v8), f9 = bf2f2(v9), fa = bf2f2(va), fb = bf2f2(vb);
        float2 fc = bf2f2(vc), fd = bf2f2(vd), fe = bf2f2(ve), ff = bf2f2(vf);
        acc.x += ((w0 * f0.x + w1 * f1.x) + (w2 * f2.x + w3 * f3.x)) +
                 ((w4 * f4.x + w5 * f5.x) + (w6 * f6.x + w7 * f7.x)) +
                 ((w8 * f8.x + w9 * f9.x) + (wa * fa.x + wb * fb.x)) +
                 ((wc * fc.x + wd * fd.x) + (we * fe.x + wf * ff.x));
        acc.y += ((w0 * f0.y + w1 * f1.y) + (w2 * f2.y + w3 * f3.y)) +
                 ((w4 * f4.y + w5 * f5.y) + (w6 * f6.y + w7 * f7.y)) +
                 ((w8 * f8.y + w9 * f9.y) + (wa * fa.y + wb * fb.y)) +
                 ((wc * fc.y + wd * fd.y) + (we * fe.y + wf * ff.y));
    }
    if (e < end) {  // one trailing 8-batch
        int4 c0 = *(const int4*)(csr + e);
        int4 c1 = *(const int4*)(csr + e + 4);
        unsigned int v0 = hbA[(size_t)c0.x * 64 + j];
        unsigned int v1 = hbA[(size_t)c0.y * 64 + j];
        unsigned int v2 = hbA[(size_t)c0.z * 64 + j];
        unsigned int v3 = hbA[(size_t)c0.w * 64 + j];
        unsigned int v4 = hbA[(size_t)c1.x * 64 + j];
        unsigned int v5 = hbA[(size_t)c1.y * 64 + j];
        unsigned int v6 = hbA[(size_t)c1.z * 64 + j];
        unsigned int v7 = hbA[(size_t)c1.w * 64 + j];
        float w0 = dinv[c0.x], w1 = dinv[c0.y], w2 = dinv[c0.z], w3 = dinv[c0.w];
        float w4 = dinv[c1.x], w5 = dinv[c1.y], w6 = dinv[c1.z], w7 = dinv[c1.w];
        float2 f0 = bf2f2(v0), f1 = bf2f2(v1), f2 = bf2f2(v2), f3 = bf2f2(v3);
        float2 f4 = bf2f2(v4), f5 = bf2f2(v5), f6 = bf2f2(v6), f7 = bf2f2(v7);
        acc.x += ((w0 * f0.x + w1 * f1.x) + (w2 * f2.x + w3 * f3.x)) +
                 ((w4 * f4.x + w5 * f5.x) + (w6 * f6.x + w7 * f7.x));
        acc.y += ((w0 * f0.y + w1 * f1.y) + (w2 * f2.y + w3 * f3.y)) +
                 ((w4 * f4.y + w5 * f5.y) + (w6 * f6.y + w7 * f7.y));
    }
    float2 bb = bias2[j];
    float ox = fmaxf(dv * acc.x + bb.x, 0.0f);
    float oy = fmaxf(dv * acc.y + bb.y, 0.0f);
    xact[(size_t)d * 64 + j] = f2bf2(ox, oy);
    __syncthreads();                     // all 4 rows of this block written (vmcnt drained)
    if (threadIdx.x == 0) {
        __threadfence();                 // release: xact stores visible before count
        atomicAdd(&cnt[blockIdx.x >> 2], 1);
    }
}

// ---------------- fused 2: unweighted agg (layer 2) + gemm3 ------------------
// Same structure; hbB holds pre-scaled hs (gemm2 epilogue), so the gather is
// pure adds (round-0 exact). gemm3 writes hbA (dead after fused 1).

__global__ __launch_bounds__(256) void agg_gemm3_kernel(const unsigned int* __restrict__ hbB,
                                                        const int* __restrict__ csr,
                                                        const int* __restrict__ info,
                                                        const float* __restrict__ dinv,
                                                        const float2* __restrict__ bias2,
                                                        unsigned int* __restrict__ xact,
                                                        const unsigned short* __restrict__ wt3,
                                                        unsigned int* __restrict__ hbA,
                                                        int* __restrict__ cnt) {
    if (blockIdx.x >= AGGB) {             // ---- gemm3 family ----
        const int ws = (blockIdx.x - AGGB) * 4 + (threadIdx.x >> 6);
        const int m0 = ws * 16;
        if (m0 >= NN) return;
        wait_group16(cnt, ws);
        __threadfence();
        gemm16_scaled(m0, xact, wt3, dinv, hbA);
        return;
    }
    const int d = blockIdx.x * 4 + (threadIdx.x >> 6);
    const int j = threadIdx.x & 63;     // lane
    const int ifo = info[d];
    int e = ifo >> 8;
    const int end = e + (((ifo & 255) + 7) & ~7);
    float2 acc = bf2f2(hbB[(size_t)d * 64 + j]);   // self term: hs[d]
    for (; e + 16 <= end; e += 16) {
        int4 c0 = *(const int4*)(csr + e);
        int4 c1 = *(const int4*)(csr + e + 4);
        int4 c2 = *(const int4*)(csr + e + 8);
        int4 c3 = *(const int4*)(csr + e + 12);
        unsigned int v0 = hbB[(size_t)c0.x * 64 + j];
        unsigned int v1 = hbB[(size_t)c0.y * 64 + j];
        unsigned int v2 = hbB[(size_t)c0.z * 64 + j];
        unsigned int v3 = hbB[(size_t)c0.w * 64 + j];
        unsigned int v4 = hbB[(size_t)c1.x * 64 + j];
        unsigned int v5 = hbB[(size_t)c1.y * 64 + j];
        unsigned int v6 = hbB[(size_t)c1.z * 64 + j];
        unsigned int v7 = hbB[(size_t)c1.w * 64 + j];
        unsigned int v8 = hbB[(size_t)c2.x * 64 + j];
        unsigned int v9 = hbB[(size_t)c2.y * 64 + j];
        unsigned int va = hbB[(size_t)c2.z * 64 + j];
        unsigned int vb = hbB[(size_t)c2.w * 64 + j];
        unsigned int vc = hbB[(size_t)c3.x * 64 + j];
        unsigned int vd = hbB[(size_t)c3.y * 64 + j];
        unsigned int ve = hbB[(size_t)c3.z * 64 + j];
        unsigned int vf = hbB[(size_t)c3.w * 64 + j];
        float2 f0 = bf2f2(v0), f1 = bf2f2(v1), f2 = bf2f2(v2), f3 = bf2f2(v3);
        float2 f4 = bf2f2(v4), f5 = bf2f2(v5), f6 = bf2f2(v6), f7 = bf2f2(v7);
        float2 f8 = bf2f2(v8), f9 = bf2f2(v9), fa = bf2f2(va), fb = bf2f2(vb);
        float2 fc = bf2f2(vc), fd = bf2f2(vd), fe = bf2f2(ve), ff = bf2f2(vf);
        acc.x += ((f0.x + f1.x) + (f2.x + f3.x)) + ((f4.x + f5.x) + (f6.x + f7.x)) +
                 ((f8.x + f9.x) + (fa.x + fb.x)) + ((fc.x + fd.x) + (fe.x + ff.x));
        acc.y += ((f0.y + f1.y) + (f2.y + f3.y)) + ((f4.y + f5.y) + (f6.y + f7.y)) +
                 ((f8.y + f9.y) + (fa.y + fb.y)) + ((fc.y + fd.y) + (fe.y + ff.y));
    }
    if (e < end) {  // one trailing 8-batch
        int4 c0 = *(const int4*)(csr + e);
        int4 c1 = *(const int4*)(csr + e + 4);
        unsigned int v0 = hbB[(size_t)c0.x * 64 + j];
        unsigned int v1 = hbB[(size_t)c0.y * 64 + j];
        unsigned int v2 = hbB[(size_t)c0.z * 64 + j];
        unsigned int v3 = hbB[(size_t)c0.w * 64 + j];
        unsigned int v4 = hbB[(size_t)c1.x * 64 + j];
        unsigned int v5 = hbB[(size_t)c1.y * 64 + j];
        unsigned int v6 = hbB[(size_t)c1.z * 64 + j];
        unsigned int v7 = hbB[(size_t)c1.w * 64 + j];
        float2 f0 = bf2f2(v0), f1 = bf2f2(v1), f2 = bf2f2(v2), f3 = bf2f2(v3);
        float2 f4 = bf2f2(v4), f5 = bf2f2(v5), f6 = bf2f2(v6), f7 = bf2f2(v7);
        acc.x += ((f0.x + f1.x) + (f2.x + f3.x)) + ((f4.x + f5.x) + (f6.x + f7.x));
        acc.y += ((f0.y + f1.y) + (f2.y + f3.y)) + ((f4.y + f5.y) + (f6.y + f7.y));
    }
    const float dv = dinv[d];
    float2 bb = bias2[j];
    float ox = fmaxf(dv * acc.x + bb.x, 0.0f);
    float oy = fmaxf(dv * acc.y + bb.y, 0.0f);
    xact[(size_t)d * 64 + j] = f2bf2(ox, oy);
    __syncthreads();
    if (threadIdx.x == 0) {
        __threadfence();
        atomicAdd(&cnt[blockIdx.x >> 2], 1);
    }
}

// ---------------- final aggregation (layer 3): round-0 exact, fp32 out -------

__global__ __launch_bounds__(256) void aggregate_f_kernel(const unsigned int* __restrict__ hb,
                                                          const int* __restrict__ csr,
                                                          const int* __restrict__ info,
                                                          const float* __restrict__ dinv,
                                                          const float2* __restrict__ bias2,
                                                          float2* __restrict__ outp) {
    const int d = blockIdx.x * 4 + (threadIdx.x >> 6);
    const int j = threadIdx.x & 63;     // lane
    const int ifo = info[d];
    int e = ifo >> 8;
    const int end = e + (((ifo & 255) + 7) & ~7);
    float2 acc = bf2f2(hb[(size_t)d * 64 + j]);   // self term: hs[d]
    for (; e + 16 <= end; e += 16) {
        int4 c0 = *(const int4*)(csr + e);
        int4 c1 = *(const int4*)(csr + e + 4);
        int4 c2 = *(const int4*)(csr + e + 8);
        int4 c3 = *(const int4*)(csr + e + 12);
        unsigned int v0 = hb[(size_t)c0.x * 64 + j];
        unsigned int v1 = hb[(size_t)c0.y * 64 + j];
        unsigned int v2 = hb[(size_t)c0.z * 64 + j];
        unsigned int v3 = hb[(size_t)c0.w * 64 + j];
        unsigned int v4 = hb[(size_t)c1.x * 64 + j];
        unsigned int v5 = hb[(size_t)c1.y * 64 + j];
        unsigned int v6 = hb[(size_t)c1.z * 64 + j];
        unsigned int v7 = hb[(size_t)c1.w * 64 + j];
        unsigned int v8 = hb[(size_t)c2.x * 64 + j];
        unsigned int v9 = hb[(size_t)c2.y * 64 + j];
        unsigned int va = hb[(size_t)c2.z * 64 + j];
        unsigned int vb = hb[(size_t)c2.w * 64 + j];
        unsigned int vc = hb[(size_t)c3.x * 64 + j];
        unsigned int vd = hb[(size_t)c3.y * 64 + j];
        unsigned int ve = hb[(size_t)c3.z * 64 + j];
        unsigned int vf = hb[(size_t)c3.w * 64 + j];
        float2 f0 = bf2f2(v0), f1 = bf2f2(v1), f2 = bf2f2(v2), f3 = bf2f2(v3);
        float2 f4 = bf2f2(v4), f5 = bf2f2(v5), f6 = bf2f2(v6), f7 = bf2f2(v7);
        float2 f8 = bf2f2(v8), f9 = bf2f2(v9), fa = bf2f2(va), fb = bf2f2(vb);
        float2 fc = bf2f2(vc), fd = bf2f2(vd), fe = bf2f2(ve), ff = bf2f2(vf);
        acc.x += ((f0.x + f1.x) + (f2.x + f3.x)) + ((f4.x + f5.x) + (f6.x + f7.x)) +
                 ((f8.x + f9.x) + (fa.x + fb.x)) + ((fc.x + fd.x) + (fe.x + ff.x));
        acc.y += ((f0.y + f1.y) + (f2.y + f3.y)) + ((f4.y + f5.y) + (f6.y + f7.y)) +
                 ((f8.y + f9.y) + (fa.y + fb.y)) + ((fc.y + fd.y) + (fe.y + ff.y));
    }
    if (e < end) {  // one trailing 8-batch
        int4 c0 = *(const int4*)(csr + e);
        int4 c1 = *(const int4*)(csr + e + 4);
        unsigned int v0 = hb[(size_t)c0.x * 64 + j];
        unsigned int v1 = hb[(size_t)c0.y * 64 + j];
        unsigned int v2 = hb[(size_t)c0.z * 64 + j];
        unsigned int v3 = hb[(size_t)c0.w * 64 + j];
        unsigned int v4 = hb[(size_t)c1.x * 64 + j];
        unsigned int v5 = hb[(size_t)c1.y * 64 + j];
        unsigned int v6 = hb[(size_t)c1.z * 64 + j];
        unsigned int v7 = hb[(size_t)c1.w * 64 + j];
        float2 f0 = bf2f2(v0), f1 = bf2f2(v1), f2 = bf2f2(v2), f3 = bf2f2(v3);
        float2 f4 = bf2f2(v4), f5 = bf2f2(v5), f6 = bf2f2(v6), f7 = bf2f2(v7);
        acc.x += ((f0.x + f1.x) + (f2.x + f3.x)) + ((f4.x + f5.x) + (f6.x + f7.x));
        acc.y += ((f0.y + f1.y) + (f2.y + f3.y)) + ((f4.y + f5.y) + (f6.y + f7.y));
    }
    const float dv = dinv[d];
    float2 bb = bias2[j];
    outp[(size_t)d * 64 + j] = make_float2(fmaxf(dv * acc.x + bb.x, 0.0f),
                                           fmaxf(dv * acc.y + bb.y, 0.0f));
}

// ---------------- launch ----------------

extern "C" void kernel_launch(void* const* d_in, const int* in_sizes, int n_in,
                              void* d_out, int out_size, void* d_ws, size_t ws_size,
                              hipStream_t stream) {
    const float* x0 = (const float*)d_in[0];
    const int* ei = (const int*)d_in[1];   // int32 on device (harness contract)
    const float* W1 = (const float*)d_in[2];
    const float* b1 = (const float*)d_in[3];
    const float* W2 = (const float*)d_in[4];
    const float* b2 = (const float*)d_in[5];
    const float* W3 = (const float*)d_in[6];
    const float* b3 = (const float*)d_in[7];
    float* out = (float*)d_out;

    char* ws = (char*)d_ws;
    size_t off = 0;
    auto alloc = [&](size_t bytes) -> void* {
        off = (off + 511) & ~(size_t)511;
        void* p = ws + off;
        off += bytes;
        return p;
    };
    unsigned int* hbA = (unsigned int*)alloc(((size_t)NN + 1) * 64 * 4);  // 25.6 MB (+ zero row)
    unsigned int* hbB = (unsigned int*)alloc(((size_t)NN + 1) * 64 * 4);  // 25.6 MB (+ zero row)
    int* csr = (int*)alloc((size_t)NSB * RCAP * sizeof(int));             // 16.8 MB compact
    uint2* buckets2 = (uint2*)alloc((size_t)NSB * SCAP * sizeof(uint2));  // 16.8 MB
    int* info = (int*)alloc((size_t)NN * sizeof(int));
    float* dinv = (float*)alloc(((size_t)NN + 1) * sizeof(float));        // + sentinel 0
    int* zone = (int*)alloc((NSB + 2 * NG16) * sizeof(int));              // gcur2|cntA|cntB
    unsigned short* wt1 = (unsigned short*)alloc(128 * 128 * 2);
    unsigned short* wt2 = (unsigned short*)alloc(128 * 128 * 2);
    unsigned short* wt3 = (unsigned short*)alloc(128 * 128 * 2);

    int* gcur2 = zone;
    int* cntA = zone + NSB;
    int* cntB = cntA + NG16;

    // bf16 activation ping buffer lives in d_out's first 25.6 MB (dead by agg3)
    unsigned int* xact = (unsigned int*)d_out;

    const int4* src4 = (const int4*)ei;          // edge_index[0]
    const int4* dst4 = (const int4*)(ei + EE);   // edge_index[1]

    // graph prep (redone every call: ws is re-poisoned)
    hipMemsetAsync(zone, 0, (NSB + 2 * NG16) * sizeof(int), stream);
    fbwt_kernel<<<WTB + 512, 256, 0, stream>>>(src4, dst4, gcur2, buckets2,
                                               W1, W2, W3, wt1, wt2, wt3, hbA, hbB, dinv);
    sort3_gemm1_kernel<<<903, 256, 0, stream>>>(buckets2, gcur2, csr, info, dinv,
                                                x0, wt1, hbA);
    // layer-1 aggregate + layer-2 GEMM overlapped via per-group done-counters
    aggw_gemm2_kernel<<<AGGB + GEMB, 256, 0, stream>>>(hbA, csr, info, dinv,
                                                       (const float2*)b1, xact,
                                                       wt2, hbB, cntA);
    // layer-2 aggregate + layer-3 GEMM overlapped
    agg_gemm3_kernel<<<AGGB + GEMB, 256, 0, stream>>>(hbB, csr, info, dinv,
                                                      (const float2*)b2, xact,
                                                      wt3, hbA, cntB);
    // layer-3 aggregate -> fp32 output
    aggregate_f_kernel<<<AGGB, 256, 0, stream>>>(hbA, csr, info, dinv,
                                                 (const float2*)b3, (float2*)out);
}

// Round 12
// 399.824 us; speedup vs baseline: 5.6507x; 5.6507x over previous
//
#include <hip/hip_runtime.h>

#define NN 100000
#define EE 1600000
#define NPART 8                   // dst-space partitions
#define PSZ (NN / NPART)          // 12500 nodes per partition
#define NI4 (EE / 4)              // 400000 int4 records in dst/src
#define SUBW 196                  // dst nodes per sub-bucket (64 per partition)
#define NSB (NPART * 64)          // 512 sub-buckets
#define SCAP 4096                 // records per sub-bucket (exp 3136, +17 sigma)
#define RCAP 8192                 // csr slots per sub-bucket region (exp ~3960)
#define LBCAP 96                  // LDS bin capacity (round-0 proven)
#define WTB 48                    // 3 matrices x 16 (32x32) transpose tiles

typedef __attribute__((ext_vector_type(8))) short bf16x8;
typedef __attribute__((ext_vector_type(4))) float f32x4;

// bf16 helpers (exact unpack; RN pack)
__device__ inline unsigned int f2bf2(float a, float b) {  // pack (a=low, b=high)
    unsigned int ua = __float_as_uint(a);
    unsigned int ub = __float_as_uint(b);
    ua = (ua + 0x7fffu + ((ua >> 16) & 1u)) >> 16;
    ub = (ub + 0x7fffu + ((ub >> 16) & 1u)) >> 16;
    return ua | (ub << 16);
}
__device__ inline unsigned short f2bf(float a) {
    unsigned int u = __float_as_uint(a);
    return (unsigned short)((u + 0x7fffu + ((u >> 16) & 1u)) >> 16);
}
__device__ inline float2 bf2f2(unsigned int u) {
    return make_float2(__uint_as_float(u << 16), __uint_as_float(u & 0xffff0000u));
}

// ---------------- K1: wt-build (blocks 0-47) + round-0 filterbin (48-559) ----
// Lean: no deg atomics (rounds 4/6: ~20 us in any placement). Block 0 zeros
// the hb sentinel row and dinv[NN].

__global__ __launch_bounds__(256) void fbwt_kernel(const int4* __restrict__ src4,
                                                   const int4* __restrict__ dst4,
                                                   int* __restrict__ gcur2,
                                                   uint2* __restrict__ buckets2,
                                                   const float* __restrict__ W1,
                                                   const float* __restrict__ W2,
                                                   const float* __restrict__ W3,
                                                   unsigned short* __restrict__ wt1,
                                                   unsigned short* __restrict__ wt2,
                                                   unsigned short* __restrict__ wt3,
                                                   unsigned int* __restrict__ hb,
                                                   float* __restrict__ dinv) {
    __shared__ uint2 bins[64][LBCAP];
    __shared__ int bcnt[64];
    __shared__ int gbase[64];
    __shared__ float tile[32][33];
    const int bx = blockIdx.x;

    if (bx < WTB) {                       // ---- wt-build blocks ----
        const int m = bx >> 4;            // matrix 0..2
        const int tl = bx & 15;           // 32x32 tile
        const int ti = tl >> 2, tj = tl & 3;
        const float* W = m == 0 ? W1 : (m == 1 ? W2 : W3);
        unsigned short* wt = m == 0 ? wt1 : (m == 1 ? wt2 : wt3);
        const int r = threadIdx.x >> 5, c = threadIdx.x & 31;
#pragma unroll
        for (int rr = r; rr < 32; rr += 8)     // coalesced read of W[k][n]
            tile[rr][c] = W[(ti * 32 + rr) * 128 + tj * 32 + c];
        __syncthreads();
#pragma unroll
        for (int rr = r; rr < 32; rr += 8)     // coalesced write of wt[n][k]
            wt[(size_t)(tj * 32 + rr) * 128 + ti * 32 + c] = f2bf(tile[c][rr]);
        if (bx == 0) {
            if (threadIdx.x < 64) hb[(size_t)NN * 64 + threadIdx.x] = 0;
            if (threadIdx.x == 64) dinv[NN] = 0.0f;
        }
        return;
    }

    // ---- filter blocks (round-0 exact config: 512 blocks, LBCAP 96) ----
    const int fb = bx - WTB;
    const int p = fb >> 6;
    const int c = fb & 63;
    if (threadIdx.x < 64) bcnt[threadIdx.x] = 0;
    __syncthreads();
    const int lo = p * PSZ, hi = lo + PSZ;
    const int chunk4 = NI4 / 64;                    // 6250, exact
    const int a0 = c * chunk4, a1 = a0 + chunk4;
    for (int i = a0 + threadIdx.x; i < a1; i += 256) {
        int4 d4 = dst4[i];
        bool m0 = (d4.x >= lo && d4.x < hi);
        bool m1 = (d4.y >= lo && d4.y < hi);
        bool m2 = (d4.z >= lo && d4.z < hi);
        bool m3 = (d4.w >= lo && d4.w < hi);
        if (!(m0 | m1 | m2 | m3)) continue;
        int4 s4 = src4[i];
        int ss[4] = {s4.x, s4.y, s4.z, s4.w};
        int dd[4] = {d4.x, d4.y, d4.z, d4.w};
        bool mm[4] = {m0, m1, m2, m3};
#pragma unroll
        for (int k = 0; k < 4; ++k) {
            if (!mm[k]) continue;
            int li = (dd[k] - lo) / SUBW;           // 0..63
            int pos = atomicAdd(&bcnt[li], 1);
            if (pos < LBCAP) {
                bins[li][pos] = make_uint2((unsigned)ss[k], (unsigned)dd[k]);
            } else {                                 // rare overflow: direct append
                int sb = p * 64 + li;
                int gp = atomicAdd(&gcur2[sb], 1);
                buckets2[(size_t)sb * SCAP + gp] = make_uint2((unsigned)ss[k], (unsigned)dd[k]);
            }
        }
    }
    __syncthreads();
    if (threadIdx.x < 64) {
        int cc = min(bcnt[threadIdx.x], LBCAP);
        gbase[threadIdx.x] = atomicAdd(&gcur2[p * 64 + threadIdx.x], cc);
        bcnt[threadIdx.x] = cc;
    }
    __syncthreads();
    for (int b = 0; b < 64; ++b) {
        const int cc = bcnt[b];
        uint2* outp = buckets2 + (size_t)(p * 64 + b) * SCAP + gbase[b];
        for (int i = threadIdx.x; i < cc; i += 256) outp[i] = bins[b][i];
    }
}

// ---------------- GEMM body: hb(bf16) = [dinv[row] *] (x @ W) via MFMA -------
// 64 rows per wave, W-fragments hoisted once into registers. (256,2): 256-VGPR
// cap, no spill. SCALE=false for layer 1 (dinv not ready -> raw h; aggregate 1
// applies weights); SCALE=true for layers 2/3 (round-0 exact math).

template <bool F32IN, bool SCALE>
__device__ __forceinline__ void gemm_body(int wave, const void* __restrict__ xin,
                                          const unsigned short* __restrict__ wt,
                                          const float* __restrict__ dinv,
                                          unsigned int* __restrict__ hb) {
    const int base = wave * 64;
    if (base >= NN) return;
    const int lane = threadIdx.x & 63;
    const int r = lane & 15;
    const int q = lane >> 4;
    const unsigned short* wrow = wt + (size_t)r * 128 + q * 8;
    bf16x8 wfr[4][8];
#pragma unroll
    for (int kc = 0; kc < 4; ++kc)
#pragma unroll
        for (int nt = 0; nt < 8; ++nt)
            wfr[kc][nt] = *(const bf16x8*)(wrow + (size_t)nt * 16 * 128 + kc * 32);
#pragma unroll
    for (int tt = 0; tt < 4; ++tt) {
        const int m0 = base + tt * 16;
        if (m0 >= NN) break;
        f32x4 acc[8] = {};
#pragma unroll
        for (int kc = 0; kc < 4; ++kc) {
            bf16x8 xf;
            if (F32IN) {
                const float* xrow = (const float*)xin + (size_t)(m0 + r) * 128 + q * 8 + kc * 32;
                float4 a = *(const float4*)xrow;
                float4 b = *(const float4*)(xrow + 4);
                unsigned short tmp[8] = {f2bf(a.x), f2bf(a.y), f2bf(a.z), f2bf(a.w),
                                         f2bf(b.x), f2bf(b.y), f2bf(b.z), f2bf(b.w)};
                xf = *(const bf16x8*)tmp;
            } else {
                const unsigned short* xrow =
                    (const unsigned short*)xin + (size_t)(m0 + r) * 128 + q * 8 + kc * 32;
                xf = *(const bf16x8*)xrow;
            }
#pragma unroll
            for (int nt = 0; nt < 8; ++nt)
                acc[nt] = __builtin_amdgcn_mfma_f32_16x16x32_bf16(wfr[kc][nt], xf, acc[nt], 0, 0, 0);
        }
        const int orow = m0 + r;
        const float dvr = SCALE ? dinv[orow] : 1.0f;
        unsigned int* hrow = hb + (size_t)orow * 64;  // uint = 2 bf16
#pragma unroll
        for (int nt = 0; nt < 8; ++nt) {
            int n = nt * 16 + q * 4;
            if (SCALE) {
                *(uint2*)(hrow + (n >> 1)) =
                    make_uint2(f2bf2(acc[nt][0] * dvr, acc[nt][1] * dvr),
                               f2bf2(acc[nt][2] * dvr, acc[nt][3] * dvr));
            } else {
                *(uint2*)(hrow + (n >> 1)) =
                    make_uint2(f2bf2(acc[nt][0], acc[nt][1]), f2bf2(acc[nt][2], acc[nt][3]));
            }
        }
    }
}

// ---------------- K2: sort3 (blocks 0-511) + layer-1 GEMM (512-902) ----------
// ROUND-0 EXACT sort3: compact padded rows in csr[sb*RCAP + rstart], one
// coalesced int4 stream write, info[d] = (rowoff<<8)|deg, dinv[d]. gemm1 needs
// only wt1/x0 (complete after K1) -> fully hidden under sort3.

__global__ __launch_bounds__(256, 2) void sort3_gemm1_kernel(const uint2* __restrict__ buckets2,
                                                             const int* __restrict__ gcur2,
                                                             int* __restrict__ csr,
                                                             int* __restrict__ info,
                                                             float* __restrict__ dinv,
                                                             const float* __restrict__ x0,
                                                             const unsigned short* __restrict__ wt1,
                                                             unsigned int* __restrict__ hb) {
    __shared__ int hist[256];
    __shared__ int pscan[256];
    __shared__ int lcur[256];
    __shared__ int staged[RCAP];
    if (blockIdx.x >= 512) {   // layer-1 GEMM blocks (raw output)
        const int wave = (blockIdx.x - 512) * 4 + (threadIdx.x >> 6);
        gemm_body<true, false>(wave, (const void*)x0, wt1, nullptr, hb);
        return;
    }
    const int sb = blockIdx.x;
    const int li = sb & 63;
    const int base_node = (sb >> 6) * PSZ + li * SUBW;
    const int nnodes = min(SUBW, PSZ - li * SUBW);  // 196 (152 for last)
    const int scnt = gcur2[sb];
    const uint2* bk = buckets2 + (size_t)sb * SCAP;
    const int t = threadIdx.x;
    hist[t] = 0;
    __syncthreads();
    for (int i = t; i < scnt; i += 256) atomicAdd(&hist[(int)bk[i].y - base_node], 1);
    __syncthreads();
    const int padded = (t < nnodes) ? ((hist[t] + 7) & ~7) : 0;
    pscan[t] = padded;
    __syncthreads();
    for (int off = 1; off < 256; off <<= 1) {
        int v = (t >= off) ? pscan[t - off] : 0;
        __syncthreads();
        pscan[t] += v;
        __syncthreads();
    }
    const int rstart = pscan[t] - padded;           // exclusive scan
    lcur[t] = rstart;
    __syncthreads();
    const int total = pscan[255];                   // multiple of 8
    for (int i = t; i < total; i += 256) staged[i] = NN;  // sentinel fill
    __syncthreads();
    for (int i = t; i < scnt; i += 256) {
        uint2 r = bk[i];
        int pos = atomicAdd(&lcur[(int)r.y - base_node], 1);
        staged[pos] = (int)r.x;
    }
    __syncthreads();
    int4* co = (int4*)(csr + (size_t)sb * RCAP);
    for (int i = t; i < (total >> 2); i += 256) co[i] = ((const int4*)staged)[i];
    if (t < nnodes) {
        int dg = hist[t];
        info[base_node + t] = ((sb * RCAP + rstart) << 8) | dg;   // rowoff<24b, deg<8b
        dinv[base_node + t] = rsqrtf(1.0f + (float)dg);
    }
}

// standalone GEMM for layers 2/3 (dinv ready -> scaled epilogue, round-0 exact)
__global__ __launch_bounds__(256, 2) void gemm_kernel(const void* __restrict__ xin,
                                                      const unsigned short* __restrict__ wt,
                                                      const float* __restrict__ dinv,
                                                      unsigned int* __restrict__ hb) {
    const int wave = blockIdx.x * 4 + (threadIdx.x >> 6);
    gemm_body<false, true>(wave, xin, wt, dinv, hb);
}

// ---------------- aggregation (layers 2/3): round-0 byte-identical -----------
// out[d] = relu( dv*(hs[d] + sum_e hs[src_e]) + b ); hs pre-scaled in GEMM.
// One node per wave, 4 waves/block, info-addressed compact rows.

template <bool BF16OUT>
__global__ __launch_bounds__(256) void aggregate_kernel(const unsigned int* __restrict__ hb,
                                                        const int* __restrict__ csr,
                                                        const int* __restrict__ info,
                                                        const float* __restrict__ dinv,
                                                        const float2* __restrict__ bias2,
                                                        void* __restrict__ outp) {
    const int d = blockIdx.x * 4 + (threadIdx.x >> 6);
    const int j = threadIdx.x & 63;     // lane
    const int ifo = info[d];
    int e = ifo >> 8;
    const int end = e + (((ifo & 255) + 7) & ~7);
    float2 acc = bf2f2(hb[(size_t)d * 64 + j]);   // self term: hs[d]
    for (; e + 16 <= end; e += 16) {
        int4 c0 = *(const int4*)(csr + e);
        int4 c1 = *(const int4*)(csr + e + 4);
        int4 c2 = *(const int4*)(csr + e + 8);
        int4 c3 = *(const int4*)(csr + e + 12);
        unsigned int v0 = hb[(size_t)c0.x * 64 + j];
        unsigned int v1 = hb[(size_t)c0.y * 64 + j];
        unsigned int v2 = hb[(size_t)c0.z * 64 + j];
        unsigned int v3 = hb[(size_t)c0.w * 64 + j];
        unsigned int v4 = hb[(size_t)c1.x * 64 + j];
        unsigned int v5 = hb[(size_t)c1.y * 64 + j];
        unsigned int v6 = hb[(size_t)c1.z * 64 + j];
        unsigned int v7 = hb[(size_t)c1.w * 64 + j];
        unsigned int v8 = hb[(size_t)c2.x * 64 + j];
        unsigned int v9 = hb[(size_t)c2.y * 64 + j];
        unsigned int va = hb[(size_t)c2.z * 64 + j];
        unsigned int vb = hb[(size_t)c2.w * 64 + j];
        unsigned int vc = hb[(size_t)c3.x * 64 + j];
        unsigned int vd = hb[(size_t)c3.y * 64 + j];
        unsigned int ve = hb[(size_t)c3.z * 64 + j];
        unsigned int vf = hb[(size_t)c3.w * 64 + j];
        float2 f0 = bf2f2(v0), f1 = bf2f2(v1), f2 = bf2f2(v2), f3 = bf2f2(v3);
        float2 f4 = bf2f2(v4), f5 = bf2f2(v5), f6 = bf2f2(v6), f7 = bf2f2(v7);
        float2 f8 = bf2f2(v8), f9 = bf2f2(v9), fa = bf2f2(va), fb = bf2f2(vb);
        float2 fc = bf2f2(vc), fd = bf2f2(vd), fe = bf2f2(ve), ff = bf2f2(vf);
        acc.x += ((f0.x + f1.x) + (f2.x + f3.x)) + ((f4.x + f5.x) + (f6.x + f7.x)) +
                 ((f8.x + f9.x) + (fa.x + fb.x)) + ((fc.x + fd.x) + (fe.x + ff.x));
        acc.y += ((f0.y + f1.y) + (f2.y + f3.y)) + ((f4.y + f5.y) + (f6.y + f7.y)) +
                 ((f8.y + f9.y) + (fa.y + fb.y)) + ((fc.y + fd.y) + (fe.y + ff.y));
    }
    if (e < end) {  // one trailing 8-batch
        int4 c0 = *(const int4*)(csr + e);
        int4 c1 = *(const int4*)(csr + e + 4);
        unsigned int v0 = hb[(size_t)c0.x * 64 + j];
        unsigned int v1 = hb[(size_t)c0.y * 64 + j];
        unsigned int v2 = hb[(size_t)c0.z * 64 + j];
        unsigned int v3 = hb[(size_t)c0.w * 64 + j];
        unsigned int v4 = hb[(size_t)c1.x * 64 + j];
        unsigned int v5 = hb[(size_t)c1.y * 64 + j];
        unsigned int v6 = hb[(size_t)c1.z * 64 + j];
        unsigned int v7 = hb[(size_t)c1.w * 64 + j];
        float2 f0 = bf2f2(v0), f1 = bf2f2(v1), f2 = bf2f2(v2), f3 = bf2f2(v3);
        float2 f4 = bf2f2(v4), f5 = bf2f2(v5), f6 = bf2f2(v6), f7 = bf2f2(v7);
        acc.x += ((f0.x + f1.x) + (f2.x + f3.x)) + ((f4.x + f5.x) + (f6.x + f7.x));
        acc.y += ((f0.y + f1.y) + (f2.y + f3.y)) + ((f4.y + f5.y) + (f6.y + f7.y));
    }
    const float dv = dinv[d];
    float2 bb = bias2[j];
    float ox = fmaxf(dv * acc.x + bb.x, 0.0f);
    float oy = fmaxf(dv * acc.y + bb.y, 0.0f);
    if (BF16OUT) {
        ((unsigned int*)outp)[(size_t)d * 64 + j] = f2bf2(ox, oy);
    } else {
        ((float2*)outp)[(size_t)d * 64 + j] = make_float2(ox, oy);
    }
}

// ---------------- weighted aggregation (layer 1 only) ------------------------
// hb holds raw h; gather applies dinv[src] per edge (L2-resident broadcast
// loads) + dinv[d] on the self term. SEPARATE kernel name (not a template
// sibling) so its codegen can't perturb the unweighted variant's regalloc.

__global__ __launch_bounds__(256) void aggregate_w_kernel(const unsigned int* __restrict__ hb,
                                                          const int* __restrict__ csr,
                                                          const int* __restrict__ info,
                                                          const float* __restrict__ dinv,
                                                          const float2* __restrict__ bias2,
                                                          unsigned int* __restrict__ outp) {
    const int d = blockIdx.x * 4 + (threadIdx.x >> 6);
    const int j = threadIdx.x & 63;     // lane
    const int ifo = info[d];
    int e = ifo >> 8;
    const int end = e + (((ifo & 255) + 7) & ~7);
    const float dv = dinv[d];
    float2 acc;
    {
        float2 s = bf2f2(hb[(size_t)d * 64 + j]);
        acc.x = dv * s.x;
        acc.y = dv * s.y;
    }
    for (; e + 16 <= end; e += 16) {
        int4 c0 = *(const int4*)(csr + e);
        int4 c1 = *(const int4*)(csr + e + 4);
        int4 c2 = *(const int4*)(csr + e + 8);
        int4 c3 = *(const int4*)(csr + e + 12);
        unsigned int v0 = hb[(size_t)c0.x * 64 + j];
        unsigned int v1 = hb[(size_t)c0.y * 64 + j];
        unsigned int v2 = hb[(size_t)c0.z * 64 + j];
        unsigned int v3 = hb[(size_t)c0.w * 64 + j];
        unsigned int v4 = hb[(size_t)c1.x * 64 + j];
        unsigned int v5 = hb[(size_t)c1.y * 64 + j];
        unsigned int v6 = hb[(size_t)c1.z * 64 + j];
        unsigned int v7 = hb[(size_t)c1.w * 64 + j];
        unsigned int v8 = hb[(size_t)c2.x * 64 + j];
        unsigned int v9 = hb[(size_t)c2.y * 64 + j];
        unsigned int va = hb[(size_t)c2.z * 64 + j];
        unsigned int vb = hb[(size_t)c2.w * 64 + j];
        unsigned int vc = hb[(size_t)c3.x * 64 + j];
        unsigned int vd = hb[(size_t)c3.y * 64 + j];
        unsigned int ve = hb[(size_t)c3.z * 64 + j];
        unsigned int vf = hb[(size_t)c3.w * 64 + j];
        float w0 = dinv[c0.x], w1 = dinv[c0.y], w2 = dinv[c0.z], w3 = dinv[c0.w];
        float w4 = dinv[c1.x], w5 = dinv[c1.y], w6 = dinv[c1.z], w7 = dinv[c1.w];
        float w8 = dinv[c2.x], w9 = dinv[c2.y], wa = dinv[c2.z], wb = dinv[c2.w];
        float wc = dinv[c3.x], wd = dinv[c3.y], we = dinv[c3.z], wf = dinv[c3.w];
        float2 f0 = bf2f2(v0), f1 = bf2f2(v1), f2 = bf2f2(v2), f3 = bf2f2(v3);
        float2 f4 = bf2f2(v4), f5 = bf2f2(v5), f6 = bf2f2(v6), f7 = bf2f2(v7);
        float2 f8 = bf2f2(v8), f9 = bf2f2(v9), fa = bf2f2(va), fb = bf2f2(vb);
        float2 fc = bf2f2(vc), fd = bf2f2(vd), fe = bf2f2(ve), ff = bf2f2(vf);
        acc.x += ((w0 * f0.x + w1 * f1.x) + (w2 * f2.x + w3 * f3.x)) +
                 ((w4 * f4.x + w5 * f5.x) + (w6 * f6.x + w7 * f7.x)) +
                 ((w8 * f8.x + w9 * f9.x) + (wa * fa.x + wb * fb.x)) +
                 ((wc * fc.x + wd * fd.x) + (we * fe.x + wf * ff.x));
        acc.y += ((w0 * f0.y + w1 * f1.y) + (w2 * f2.y + w3 * f3.y)) +
                 ((w4 * f4.y + w5 * f5.y) + (w6 * f6.y + w7 * f7.y)) +
                 ((w8 * f8.y + w9 * f9.y) + (wa * fa.y + wb * fb.y)) +
                 ((wc * fc.y + wd * fd.y) + (we * fe.y + wf * ff.y));
    }
    if (e < end) {  // one trailing 8-batch
        int4 c0 = *(const int4*)(csr + e);
        int4 c1 = *(const int4*)(csr + e + 4);
        unsigned int v0 = hb[(size_t)c0.x * 64 + j];
        unsigned int v1 = hb[(size_t)c0.y * 64 + j];
        unsigned int v2 = hb[(size_t)c0.z * 64 + j];
        unsigned int v3 = hb[(size_t)c0.w * 64 + j];
        unsigned int v4 = hb[(size_t)c1.x * 64 + j];
        unsigned int v5 = hb[(size_t)c1.y * 64 + j];
        unsigned int v6 = hb[(size_t)c1.z * 64 + j];
        unsigned int v7 = hb[(size_t)c1.w * 64 + j];
        float w0 = dinv[c0.x], w1 = dinv[c0.y], w2 = dinv[c0.z], w3 = dinv[c0.w];
        float w4 = dinv[c1.x], w5 = dinv[c1.y], w6 = dinv[c1.z], w7 = dinv[c1.w];
        float2 f0 = bf2f2(v0), f1 = bf2f2(v1), f2 = bf2f2(v2), f3 = bf2f2(v3);
        float2 f4 = bf2f2(v4), f5 = bf2f2(v5), f6 = bf2f2(v6), f7 = bf2f2(v7);
        acc.x += ((w0 * f0.x + w1 * f1.x) + (w2 * f2.x + w3 * f3.x)) +
                 ((w4 * f4.x + w5 * f5.x) + (w6 * f6.x + w7 * f7.x));
        acc.y += ((w0 * f0.y + w1 * f1.y) + (w2 * f2.y + w3 * f3.y)) +
                 ((w4 * f4.y + w5 * f5.y) + (w6 * f6.y + w7 * f7.y));
    }
    float2 bb = bias2[j];
    float ox = fmaxf(dv * acc.x + bb.x, 0.0f);
    float oy = fmaxf(dv * acc.y + bb.y, 0.0f);
    outp[(size_t)d * 64 + j] = f2bf2(ox, oy);
}

// ---------------- launch ----------------

extern "C" void kernel_launch(void* const* d_in, const int* in_sizes, int n_in,
                              void* d_out, int out_size, void* d_ws, size_t ws_size,
                              hipStream_t stream) {
    const float* x0 = (const float*)d_in[0];
    const int* ei = (const int*)d_in[1];   // int32 on device (harness contract)
    const float* W1 = (const float*)d_in[2];
    const float* b1 = (const float*)d_in[3];
    const float* W2 = (const float*)d_in[4];
    const float* b2 = (const float*)d_in[5];
    const float* W3 = (const float*)d_in[6];
    const float* b3 = (const float*)d_in[7];
    float* out = (float*)d_out;

    char* ws = (char*)d_ws;
    size_t off = 0;
    auto alloc = [&](size_t bytes) -> void* {
        off = (off + 511) & ~(size_t)511;
        void* p = ws + off;
        off += bytes;
        return p;
    };
    unsigned int* hb = (unsigned int*)alloc(((size_t)NN + 1) * 64 * 4);   // 25.6 MB (+ zero row)
    int* csr = (int*)alloc((size_t)NSB * RCAP * sizeof(int));             // 16.8 MB compact
    uint2* buckets2 = (uint2*)alloc((size_t)NSB * SCAP * sizeof(uint2));  // 16.8 MB
    int* info = (int*)alloc((size_t)NN * sizeof(int));
    float* dinv = (float*)alloc(((size_t)NN + 1) * sizeof(float));        // + sentinel 0
    int* gcur2 = (int*)alloc(NSB * sizeof(int));
    unsigned short* wt1 = (unsigned short*)alloc(128 * 128 * 2);
    unsigned short* wt2 = (unsigned short*)alloc(128 * 128 * 2);
    unsigned short* wt3 = (unsigned short*)alloc(128 * 128 * 2);

    // bf16 activation ping buffer for layers 1-2 lives in d_out's first 25.6 MB
    unsigned int* xact = (unsigned int*)d_out;

    const int4* src4 = (const int4*)ei;          // edge_index[0]
    const int4* dst4 = (const int4*)(ei + EE);   // edge_index[1]

    // graph prep (redone every call: ws is re-poisoned)
    hipMemsetAsync(gcur2, 0, NSB * sizeof(int), stream);
    fbwt_kernel<<<WTB + 512, 256, 0, stream>>>(src4, dst4, gcur2, buckets2,
                                               W1, W2, W3, wt1, wt2, wt3, hb, dinv);
    sort3_gemm1_kernel<<<903, 256, 0, stream>>>(buckets2, gcur2, csr, info, dinv,
                                                x0, wt1, hb);
    // layer 1: raw h in hb -> weighted aggregate
    aggregate_w_kernel<<<NN / 4, 256, 0, stream>>>(hb, csr, info, dinv,
                                                   (const float2*)b1, xact);
    // layer 2: scaled GEMM epilogue -> round-0 aggregate
    gemm_kernel<<<391, 256, 0, stream>>>((const void*)xact, wt2, dinv, hb);
    aggregate_kernel<true><<<NN / 4, 256, 0, stream>>>(hb, csr, info, dinv,
                                                       (const float2*)b2, (void*)xact);
    // layer 3
    gemm_kernel<<<391, 256, 0, stream>>>((const void*)xact, wt3, dinv, hb);
    aggregate_kernel<false><<<NN / 4, 256, 0, stream>>>(hb, csr, info, dinv,
                                                        (const float2*)b3, (void*)out);
}